// Round 7
// baseline (4401.771 us; speedup 1.0000x reference)
//
#include <hip/hip_runtime.h>
#include <stdint.h>

typedef unsigned short u16;
typedef unsigned int   u32;
typedef unsigned long long u64;
typedef __bf16 bf16_t;
typedef bf16_t bf16x8 __attribute__((ext_vector_type(8)));
typedef float  f32x4  __attribute__((ext_vector_type(4)));
typedef int    i32x4  __attribute__((ext_vector_type(4)));

#define NSTEPS 512
#define SPIN_LIM  (1<<17)
#define RETRY_LIM (1<<13)

// ---- workspace (bytes). All ws accesses are sc1/agent-scope -> LLC is the
// single coherence point (proven path). Rings store u32 words:
// (step_tag << 16) | h_bf16  -> data is self-validating, no flags/fences.
#define WS_RING1 0u          /* [4 grp][4 slot][64 row][256 col] u32 h1 */
#define WS_RING2 1048576u    /* [4 grp][4 slot][64 row][256 col] u32 h2 */
#define WS_PROG  2097152u    /* [4 grp][64] int: L1 per-wave read progress */
#define WS_TOTAL 2098176u

#define SMEM_BYTES (64*520*2)   /* 66560: L1 weight slice (L0 uses 64*328*2) */

__device__ __forceinline__ u16 f2bf(float f) {
  u32 u = __float_as_uint(f);
  return (u16)((u + 0x7fffu + ((u >> 16) & 1u)) >> 16);   // RNE
}
__device__ __forceinline__ float bf2f(u16 b) { return __uint_as_float(((u32)b) << 16); }
__device__ __forceinline__ float sigf(float x) { return 1.f / (1.f + __expf(-x)); }
__device__ __forceinline__ float tanhf_(float x) {
  float e = __expf(-2.f * fabsf(x));
  float t = (1.f - e) / (1.f + e);
  return x >= 0.f ? t : -t;
}

__device__ __forceinline__ void st_u32_sc1(u32* p, u32 v) {
  asm volatile("global_store_dword %0, %1, off sc1" :: "v"(p), "v"(v) : "memory");
}
__device__ __forceinline__ u64 ld_u64_sc1(const u64* p) {
  u64 v; asm volatile("global_load_dwordx2 %0, %1, off sc1\n\ts_waitcnt vmcnt(0)"
                      : "=v"(v) : "v"(p) : "memory"); return v;
}

// 16 x 16B loads of a lane's 64 tagged words (8 chunks of 32 cols; lane
// covers cols quad*8..+7 of each chunk; row stride 1024B). _N = no wait
// (loads left in flight), _W = trailing vmcnt(0) drains ALL outstanding.
#define LD16_N(A, P)                                                       \
  asm volatile(                                                            \
    "global_load_dwordx4 %0,  %16, off sc1\n\t"                            \
    "global_load_dwordx4 %1,  %16, off offset:16 sc1\n\t"                  \
    "global_load_dwordx4 %2,  %16, off offset:128 sc1\n\t"                 \
    "global_load_dwordx4 %3,  %16, off offset:144 sc1\n\t"                 \
    "global_load_dwordx4 %4,  %16, off offset:256 sc1\n\t"                 \
    "global_load_dwordx4 %5,  %16, off offset:272 sc1\n\t"                 \
    "global_load_dwordx4 %6,  %16, off offset:384 sc1\n\t"                 \
    "global_load_dwordx4 %7,  %16, off offset:400 sc1\n\t"                 \
    "global_load_dwordx4 %8,  %16, off offset:512 sc1\n\t"                 \
    "global_load_dwordx4 %9,  %16, off offset:528 sc1\n\t"                 \
    "global_load_dwordx4 %10, %16, off offset:640 sc1\n\t"                 \
    "global_load_dwordx4 %11, %16, off offset:656 sc1\n\t"                 \
    "global_load_dwordx4 %12, %16, off offset:768 sc1\n\t"                 \
    "global_load_dwordx4 %13, %16, off offset:784 sc1\n\t"                 \
    "global_load_dwordx4 %14, %16, off offset:896 sc1\n\t"                 \
    "global_load_dwordx4 %15, %16, off offset:912 sc1"                     \
    : "=&v"(A[0]), "=&v"(A[1]), "=&v"(A[2]),  "=&v"(A[3]),                 \
      "=&v"(A[4]), "=&v"(A[5]), "=&v"(A[6]),  "=&v"(A[7]),                 \
      "=&v"(A[8]), "=&v"(A[9]), "=&v"(A[10]), "=&v"(A[11]),                \
      "=&v"(A[12]),"=&v"(A[13]),"=&v"(A[14]), "=&v"(A[15])                 \
    : "v"(P) : "memory")
#define LD16_W(A, P)                                                       \
  asm volatile(                                                            \
    "global_load_dwordx4 %0,  %16, off sc1\n\t"                            \
    "global_load_dwordx4 %1,  %16, off offset:16 sc1\n\t"                  \
    "global_load_dwordx4 %2,  %16, off offset:128 sc1\n\t"                 \
    "global_load_dwordx4 %3,  %16, off offset:144 sc1\n\t"                 \
    "global_load_dwordx4 %4,  %16, off offset:256 sc1\n\t"                 \
    "global_load_dwordx4 %5,  %16, off offset:272 sc1\n\t"                 \
    "global_load_dwordx4 %6,  %16, off offset:384 sc1\n\t"                 \
    "global_load_dwordx4 %7,  %16, off offset:400 sc1\n\t"                 \
    "global_load_dwordx4 %8,  %16, off offset:512 sc1\n\t"                 \
    "global_load_dwordx4 %9,  %16, off offset:528 sc1\n\t"                 \
    "global_load_dwordx4 %10, %16, off offset:640 sc1\n\t"                 \
    "global_load_dwordx4 %11, %16, off offset:656 sc1\n\t"                 \
    "global_load_dwordx4 %12, %16, off offset:768 sc1\n\t"                 \
    "global_load_dwordx4 %13, %16, off offset:784 sc1\n\t"                 \
    "global_load_dwordx4 %14, %16, off offset:896 sc1\n\t"                 \
    "global_load_dwordx4 %15, %16, off offset:912 sc1\n\t"                 \
    "s_waitcnt vmcnt(0)"                                                   \
    : "=&v"(A[0]), "=&v"(A[1]), "=&v"(A[2]),  "=&v"(A[3]),                 \
      "=&v"(A[4]), "=&v"(A[5]), "=&v"(A[6]),  "=&v"(A[7]),                 \
      "=&v"(A[8]), "=&v"(A[9]), "=&v"(A[10]), "=&v"(A[11]),                \
      "=&v"(A[12]),"=&v"(A[13]),"=&v"(A[14]), "=&v"(A[15])                 \
    : "v"(P) : "memory")

#define TAGCHK(A, TB, BAD) do {                                            \
    _Pragma("unroll")                                                      \
    for (int q_ = 0; q_ < 16; ++q_)                                        \
      BAD |= ((u32)A[q_][0] ^ TB) | ((u32)A[q_][1] ^ TB)                   \
           | ((u32)A[q_][2] ^ TB) | ((u32)A[q_][3] ^ TB);                  \
  } while (0)

// single-ring poll (L0): wait until all 64 tags == want
#define TAGPOLL(A, hp, want) do {                                          \
    u32 tb = ((u32)(want)) << 16; int it_ = 0;                             \
    for (;;) {                                                             \
      LD16_W(A, hp);                                                       \
      u32 bad = 0; TAGCHK(A, tb, bad); bad &= 0xffff0000u;                 \
      if (__all(bad == 0)) break;                                          \
      if (++it_ > RETRY_LIM) break;                                        \
      __builtin_amdgcn_s_sleep(1);                                         \
    }                                                                      \
  } while (0)

// fused dual-ring poll (L1): one LLC latency for both h1_t and h2_{t-1}
#define TAGPOLL2(A, B, pa, pb, wa, wb) do {                                \
    u32 ta = ((u32)(wa)) << 16, tb = ((u32)(wb)) << 16; int it_ = 0;       \
    for (;;) {                                                             \
      LD16_N(A, pa);                                                       \
      LD16_W(B, pb);                                                       \
      u32 bad = 0; TAGCHK(A, ta, bad); TAGCHK(B, tb, bad);                 \
      bad &= 0xffff0000u;                                                  \
      if (__all(bad == 0)) break;                                          \
      if (++it_ > RETRY_LIM) break;                                        \
      __builtin_amdgcn_s_sleep(1);                                         \
    }                                                                      \
  } while (0)

__device__ __forceinline__ bf16x8 frag_from(i32x4 lo, i32x4 hi) {
  union { u32 w[4]; bf16x8 v; } u_;
  u_.w[0] = ((u32)lo[0] & 0xffffu) | ((u32)lo[1] << 16);
  u_.w[1] = ((u32)lo[2] & 0xffffu) | ((u32)lo[3] << 16);
  u_.w[2] = ((u32)hi[0] & 0xffffu) | ((u32)hi[1] << 16);
  u_.w[3] = ((u32)hi[2] & 0xffffu) | ((u32)hi[3] << 16);
  return u_.v;
}
__device__ __forceinline__ bf16x8 pack_bf8(float4 a, float4 b) {
  union { u32 w[4]; bf16x8 v; } u_;
  u_.w[0] = (u32)f2bf(a.x) | ((u32)f2bf(a.y) << 16);
  u_.w[1] = (u32)f2bf(a.z) | ((u32)f2bf(a.w) << 16);
  u_.w[2] = (u32)f2bf(b.x) | ((u32)f2bf(b.y) << 16);
  u_.w[3] = (u32)f2bf(b.z) | ((u32)f2bf(b.w) << 16);
  return u_.v;
}

// anti-dep spin (L0, every 2nd step): lanes watch L1 read-progress words
__device__ __forceinline__ void spin64(const int* f, int lane, int target) {
  if (target <= 0) return;
  int it = 0;
  for (;;) {
    int v = __hip_atomic_load(&f[lane], __ATOMIC_RELAXED, __HIP_MEMORY_SCOPE_AGENT);
    if (__all(v >= target)) return;
    if (++it > SPIN_LIM) return;
    __builtin_amdgcn_s_sleep(2);
  }
}

__global__ void ws_init_kernel(int* p, int n) {
  int i = blockIdx.x * blockDim.x + threadIdx.x;
  if (i < n)    // agent-scope stores -> zeros at LLC (tag0 == h_{-1}=0)
    __hip_atomic_store(&p[i], 0, __ATOMIC_RELAXED, __HIP_MEMORY_SCOPE_AGENT);
}

// Pipelined persistent 2-layer LSTM, 128 blocks x 256 threads.
// blk<64: layer-0 worker; blk>=64: layer-1 worker (+ epilogue).
// b=blk&63: bi=b>>4 (batch group, 64 rows), j=b&15 (16-col slice).
// Wave wv = M-tile (16 rows). MFMA 16x16x32_bf16: A from tagged LLC ring
// (registers, no LDS staging), B from row-major padded LDS, C/D col=lane&15,
// row=quad*4+reg -> acc[nt]=gate nt, lane-local pointwise, c-state in VGPRs.
// Sync: data-embedded step tags; L1 polls BOTH rings under one vmcnt(0).
__global__ void __launch_bounds__(256, 1)
lstm_persistent(const float* __restrict__ x,
                const float* __restrict__ Wih0, const float* __restrict__ Whh0,
                const float* __restrict__ bih0, const float* __restrict__ bhh0,
                const float* __restrict__ Wih1, const float* __restrict__ Whh1,
                const float* __restrict__ bih1, const float* __restrict__ bhh1,
                const float* __restrict__ W1, const float* __restrict__ b1,
                const float* __restrict__ W2, const float* __restrict__ b2,
                float* __restrict__ out, char* __restrict__ ws)
{
  extern __shared__ u16 smem[];
  const int tid  = threadIdx.x;
  const int lane = tid & 63;
  const int wv   = tid >> 6;
  const int n16  = lane & 15;
  const int quad = lane >> 4;
  const int blk  = blockIdx.x;
  const int layer = blk >> 6;
  const int b    = blk & 63;
  const int bi   = b >> 4, j = b & 15;
  const int j16  = j * 16;
  const int rowg0 = bi * 64;
  const int widx = j*4 + wv;
  const int arow = wv*16 + n16;          // my A-row (group-local)

  u32* r1g = (u32*)(ws + WS_RING1) + (size_t)bi * 4 * 16384;
  u32* r2g = (u32*)(ws + WS_RING2) + (size_t)bi * 4 * 16384;
  int* prg = (int*)(ws + WS_PROG) + bi * 64;

  float bg[4];
  #pragma unroll
  for (int nt = 0; nt < 4; ++nt) {
    int wrow = nt*256 + j16 + n16;
    bg[nt] = layer ? (bih1[wrow] + bhh1[wrow]) : (bih0[wrow] + bhh0[wrow]);
  }
  float cst[4] = {0.f,0.f,0.f,0.f};
  i32x4 h[16];

  if (layer == 0) {
    // ---- stage W0 slice fp32->bf16 into LDS, row-major stride 328 ----
    for (int i = 0; i < 20; ++i) {
      int u = tid + i*256;               // 64 rows x 80 float4
      int lr = u / 80, c4 = u % 80;
      int wrow = (lr >> 4)*256 + j16 + (lr & 15);
      float4 v = (c4 < 16) ? *(const float4*)(Wih0 + (size_t)wrow*64 + c4*4)
                           : *(const float4*)(Whh0 + (size_t)wrow*256 + (c4-16)*4);
      u16* d = smem + lr*328 + c4*4;
      d[0]=f2bf(v.x); d[1]=f2bf(v.y); d[2]=f2bf(v.z); d[3]=f2bf(v.w);
    }
    __syncthreads();
    const u16* bP = smem + n16*328 + quad*8;

    for (int t = 0; t < NSTEPS; ++t) {
      // x_t prefetch (in flight during poll)
      const float* xp = x + ((size_t)(rowg0 + arow)*NSTEPS + t)*64 + quad*8;
      float4 xa = *(const float4*)(xp);
      float4 xb = *(const float4*)(xp + 4);
      float4 xc = *(const float4*)(xp + 32);
      float4 xd = *(const float4*)(xp + 36);
      if ((t & 1) == 0)
        spin64(prg, lane, t - 2);   // ring1 anti-dep, amortized over 2 steps
      { const char* hp = (const char*)(r1g + ((t+3)&3)*16384) + arow*1024 + quad*32;
        TAGPOLL(h, hp, t); }        // h1_{t-1}: tag t (t=0 -> zeros)
      bf16x8 a0 = pack_bf8(xa, xb), a1 = pack_bf8(xc, xd);
      f32x4 acc[4] = {{0,0,0,0},{0,0,0,0},{0,0,0,0},{0,0,0,0}};
      #pragma unroll
      for (int nt = 0; nt < 4; ++nt)
        acc[nt] = __builtin_amdgcn_mfma_f32_16x16x32_bf16(
            a0, *(const bf16x8*)(bP + nt*16*328), acc[nt], 0,0,0);
      #pragma unroll
      for (int nt = 0; nt < 4; ++nt)
        acc[nt] = __builtin_amdgcn_mfma_f32_16x16x32_bf16(
            a1, *(const bf16x8*)(bP + nt*16*328 + 32), acc[nt], 0,0,0);
      #pragma unroll
      for (int kc = 0; kc < 8; ++kc) {
        bf16x8 a = frag_from(h[2*kc], h[2*kc+1]);
        #pragma unroll
        for (int nt = 0; nt < 4; ++nt)
          acc[nt] = __builtin_amdgcn_mfma_f32_16x16x32_bf16(
              a, *(const bf16x8*)(bP + nt*16*328 + 64 + kc*32), acc[nt], 0,0,0);
      }
      u32 tag = ((u32)(t+1)) << 16;
      u32* dst = r1g + (t&3)*16384;
      #pragma unroll
      for (int r = 0; r < 4; ++r) {
        float gi = acc[0][r] + bg[0];
        float gf = acc[1][r] + bg[1];
        float gg = acc[2][r] + bg[2];
        float go = acc[3][r] + bg[3];
        float c  = sigf(gf)*cst[r] + sigf(gi)*tanhf_(gg);
        cst[r] = c;
        int rl = wv*16 + quad*4 + r;
        st_u32_sc1(dst + rl*256 + j16 + n16, tag | (u32)f2bf(sigf(go)*tanhf_(c)));
      }
      // no drain, no flag: consumers poll the tagged data itself
    }
    return;
  }

  // ======================= LAYER-1 WORKER =======================
  for (int i = 0; i < 32; ++i) {
    int u = tid + i*256;               // 64 rows x 128 float4 ([Wih1|Whh1])
    int lr = u >> 7, c4 = u & 127;
    int wrow = (lr >> 4)*256 + j16 + (lr & 15);
    float4 v = (c4 < 64) ? *(const float4*)(Wih1 + (size_t)wrow*256 + c4*4)
                         : *(const float4*)(Whh1 + (size_t)wrow*256 + (c4-64)*4);
    u16* d = smem + lr*520 + c4*4;
    d[0]=f2bf(v.x); d[1]=f2bf(v.y); d[2]=f2bf(v.z); d[3]=f2bf(v.w);
  }
  __syncthreads();
  const u16* bP = smem + n16*520 + quad*8;
  i32x4 g[16];

  for (int t = 0; t < NSTEPS; ++t) {
    // fused poll: h1_t (tag t+1) + h2_{t-1} (tag t) under ONE vmcnt(0)
    { const char* p1 = (const char*)(r1g + (t&3)*16384) + arow*1024 + quad*32;
      const char* p2 = (const char*)(r2g + ((t+3)&3)*16384) + arow*1024 + quad*32;
      TAGPOLL2(h, g, p1, p2, t+1, t); }
    if (lane == 0)                  // read-progress for L0's anti-dep
      __hip_atomic_store(&prg[widx], t+1, __ATOMIC_RELAXED, __HIP_MEMORY_SCOPE_AGENT);
    f32x4 acc[4] = {{0,0,0,0},{0,0,0,0},{0,0,0,0},{0,0,0,0}};
    #pragma unroll
    for (int kc = 0; kc < 8; ++kc) {            // h1 half
      bf16x8 a = frag_from(h[2*kc], h[2*kc+1]);
      #pragma unroll
      for (int nt = 0; nt < 4; ++nt)
        acc[nt] = __builtin_amdgcn_mfma_f32_16x16x32_bf16(
            a, *(const bf16x8*)(bP + nt*16*520 + kc*32), acc[nt], 0,0,0);
    }
    #pragma unroll
    for (int kc = 0; kc < 8; ++kc) {            // h2 half
      bf16x8 a = frag_from(g[2*kc], g[2*kc+1]);
      #pragma unroll
      for (int nt = 0; nt < 4; ++nt)
        acc[nt] = __builtin_amdgcn_mfma_f32_16x16x32_bf16(
            a, *(const bf16x8*)(bP + nt*16*520 + 256 + kc*32), acc[nt], 0,0,0);
    }
    u32 tag = ((u32)(t+1)) << 16;
    u32* dst = r2g + (t&3)*16384;
    #pragma unroll
    for (int r = 0; r < 4; ++r) {
      float gi = acc[0][r] + bg[0];
      float gf = acc[1][r] + bg[1];
      float gg = acc[2][r] + bg[2];
      float go = acc[3][r] + bg[3];
      float c  = sigf(gf)*cst[r] + sigf(gi)*tanhf_(gg);
      cst[r] = c;
      int rl = wv*16 + quad*4 + r;
      st_u32_sc1(dst + rl*256 + j16 + n16, tag | (u32)f2bf(sigf(go)*tanhf_(c)));
    }
  }

  // ============ epilogue: y = (h2_T @ W1^T + b1) @ W2^T + b2 ============
  // L1 block b handles batch rows b*4..b*4+3; h2_511 = tag 512 in slot 3.
  {
    float* lastsh = (float*)smem;                 // 4x256
    float* y1sh   = lastsh + 1024;                // 4x1280
    float* psum   = y1sh + 5120;                  // 64
    __syncthreads();
    {
      int row = tid >> 6, c = tid & 63;
      int lr = (b & 15)*4 + row;                  // group-local row
      #pragma unroll
      for (int rep = 0; rep < 2; ++rep) {
        int cc = c + rep*64;                      // u64 index: cols cc*2, cc*2+1
        const u64* p = (const u64*)((const char*)(r2g + 3*16384) + lr*1024 + cc*8);
        u64 v = 0; int it = 0;
        for (;;) {
          v = ld_u64_sc1(p);
          if (((v >> 16) & 0xffffull) == 512 && (v >> 48) == 512) break;
          if (++it > RETRY_LIM) break;
          __builtin_amdgcn_s_sleep(1);
        }
        lastsh[row*256 + cc*2 + 0] = bf2f((u16)(v & 0xffffu));
        lastsh[row*256 + cc*2 + 1] = bf2f((u16)((v >> 32) & 0xffffu));
      }
    }
    __syncthreads();
    for (int i = 0; i < 5; ++i) {
      int m = tid + i*256;
      const float* wr = W1 + (size_t)m*256;
      float a0=0.f,a1=0.f,a2=0.f,a3=0.f;
      for (int k = 0; k < 256; ++k) {
        float w = wr[k];
        a0 += w*lastsh[k];     a1 += w*lastsh[256+k];
        a2 += w*lastsh[512+k]; a3 += w*lastsh[768+k];
      }
      float bb = b1[m];
      y1sh[m] = a0+bb; y1sh[1280+m] = a1+bb; y1sh[2560+m] = a2+bb; y1sh[3840+m] = a3+bb;
    }
    __syncthreads();
    if (tid < 64) {
      int row = tid >> 4, o = (tid >> 2) & 3, q = tid & 3;
      const float* w2r = W2 + (size_t)o*1280 + q*320;
      const float* yr  = y1sh + row*1280 + q*320;
      float s = 0.f;
      for (int m = 0; m < 320; ++m) s += w2r[m]*yr[m];
      psum[tid] = s;
    }
    __syncthreads();
    if (tid < 16) {
      int row = tid >> 2, o = tid & 3;
      out[(b*4 + row)*4 + o] = b2[o] + psum[tid*4+0] + psum[tid*4+1]
                                     + psum[tid*4+2] + psum[tid*4+3];
    }
  }
}

extern "C" void kernel_launch(void* const* d_in, const int* in_sizes, int n_in,
                              void* d_out, int out_size, void* d_ws, size_t ws_size,
                              hipStream_t stream) {
  (void)in_sizes; (void)n_in; (void)out_size; (void)ws_size;
  const float* x    = (const float*)d_in[0];
  const float* Wih0 = (const float*)d_in[1];
  const float* Whh0 = (const float*)d_in[2];
  const float* bih0 = (const float*)d_in[3];
  const float* bhh0 = (const float*)d_in[4];
  const float* Wih1 = (const float*)d_in[5];
  const float* Whh1 = (const float*)d_in[6];
  const float* bih1 = (const float*)d_in[7];
  const float* bhh1 = (const float*)d_in[8];
  const float* W1   = (const float*)d_in[9];
  const float* b1   = (const float*)d_in[10];
  const float* W2   = (const float*)d_in[11];
  const float* b2   = (const float*)d_in[12];
  float* out = (float*)d_out;
  char* ws   = (char*)d_ws;

  // zero rings (tag0 == h_{-1}=0) + prog flags; ws re-poisoned every call
  hipLaunchKernelGGL(ws_init_kernel, dim3((WS_TOTAL/4 + 255)/256), dim3(256),
                     0, stream, (int*)ws, (int)(WS_TOTAL/4));

  hipFuncSetAttribute((const void*)lstm_persistent,
                      hipFuncAttributeMaxDynamicSharedMemorySize, SMEM_BYTES);

  void* args[] = { (void*)&x, (void*)&Wih0, (void*)&Whh0, (void*)&bih0, (void*)&bhh0,
                   (void*)&Wih1, (void*)&Whh1, (void*)&bih1, (void*)&bhh1,
                   (void*)&W1, (void*)&b1, (void*)&W2, (void*)&b2,
                   (void*)&out, (void*)&ws };
  // cooperative launch: all 128 blocks co-resident (<= 256 CUs)
  hipLaunchCooperativeKernel((const void*)lstm_persistent, dim3(128), dim3(256),
                             args, SMEM_BYTES, stream);
}

// Round 8
// 2830.635 us; speedup vs baseline: 1.5550x; 1.5550x over previous
//
#include <hip/hip_runtime.h>
#include <stdint.h>

typedef unsigned short u16;
typedef unsigned int   u32;
typedef unsigned long long u64;
typedef __bf16 bf16_t;
typedef bf16_t bf16x8 __attribute__((ext_vector_type(8)));
typedef float  f32x4  __attribute__((ext_vector_type(4)));
typedef int    i32x4  __attribute__((ext_vector_type(4)));

#define NSTEPS 512
#define SPIN_LIM  (1<<17)
#define RETRY_LIM (1<<13)

// ---- workspace (bytes). All ws accesses are sc1/agent-scope -> LLC is the
// single coherence point (proven path). Rings store u32 words:
// (step_tag << 16) | h_bf16  -> data is self-validating, no flags/fences.
#define WS_RING1 0u          /* [4 grp][8 slot][64 row][256 col] u32 h1 */
#define WS_RING2 2097152u    /* [4 grp][4 slot][64 row][256 col] u32 h2 */
#define WS_PROG  3145728u    /* [4 grp][64] int: L1 per-wave read progress */
#define WS_TOTAL 3146752u

#define SMEM_BYTES (64*520*2)   /* 66560: L1 weight slice (L0 uses 64*328*2) */

__device__ __forceinline__ u16 f2bf(float f) {
  u32 u = __float_as_uint(f);
  return (u16)((u + 0x7fffu + ((u >> 16) & 1u)) >> 16);   // RNE
}
__device__ __forceinline__ float bf2f(u16 b) { return __uint_as_float(((u32)b) << 16); }
__device__ __forceinline__ float sigf(float x) { return 1.f / (1.f + __expf(-x)); }
__device__ __forceinline__ float tanhf_(float x) {
  float e = __expf(-2.f * fabsf(x));
  float t = (1.f - e) / (1.f + e);
  return x >= 0.f ? t : -t;
}

__device__ __forceinline__ void st_u32_sc1(u32* p, u32 v) {
  asm volatile("global_store_dword %0, %1, off sc1" :: "v"(p), "v"(v) : "memory");
}
__device__ __forceinline__ u64 ld_u64_sc1(const u64* p) {
  u64 v; asm volatile("global_load_dwordx2 %0, %1, off sc1\n\ts_waitcnt vmcnt(0)"
                      : "=v"(v) : "v"(p) : "memory"); return v;
}

// 16 x 16B loads of a lane's 64 tagged words (8 chunks of 32 cols; lane
// covers cols quad*8..+7 of each chunk; row stride 1024B). _N = no wait
// (loads left in flight), _W = trailing vmcnt(0) -> outputs valid.
#define LD16_BODY                                                          \
    "global_load_dwordx4 %0,  %16, off sc1\n\t"                            \
    "global_load_dwordx4 %1,  %16, off offset:16 sc1\n\t"                  \
    "global_load_dwordx4 %2,  %16, off offset:128 sc1\n\t"                 \
    "global_load_dwordx4 %3,  %16, off offset:144 sc1\n\t"                 \
    "global_load_dwordx4 %4,  %16, off offset:256 sc1\n\t"                 \
    "global_load_dwordx4 %5,  %16, off offset:272 sc1\n\t"                 \
    "global_load_dwordx4 %6,  %16, off offset:384 sc1\n\t"                 \
    "global_load_dwordx4 %7,  %16, off offset:400 sc1\n\t"                 \
    "global_load_dwordx4 %8,  %16, off offset:512 sc1\n\t"                 \
    "global_load_dwordx4 %9,  %16, off offset:528 sc1\n\t"                 \
    "global_load_dwordx4 %10, %16, off offset:640 sc1\n\t"                 \
    "global_load_dwordx4 %11, %16, off offset:656 sc1\n\t"                 \
    "global_load_dwordx4 %12, %16, off offset:768 sc1\n\t"                 \
    "global_load_dwordx4 %13, %16, off offset:784 sc1\n\t"                 \
    "global_load_dwordx4 %14, %16, off offset:896 sc1\n\t"                 \
    "global_load_dwordx4 %15, %16, off offset:912 sc1"
#define LD16_OUTS(A)                                                       \
      "=&v"(A[0]), "=&v"(A[1]), "=&v"(A[2]),  "=&v"(A[3]),                 \
      "=&v"(A[4]), "=&v"(A[5]), "=&v"(A[6]),  "=&v"(A[7]),                 \
      "=&v"(A[8]), "=&v"(A[9]), "=&v"(A[10]), "=&v"(A[11]),                \
      "=&v"(A[12]),"=&v"(A[13]),"=&v"(A[14]), "=&v"(A[15])

#define LD16_N(A, P) \
  asm volatile(LD16_BODY : LD16_OUTS(A) : "v"(P) : "memory")
#define LD16_W(A, P) \
  asm volatile(LD16_BODY "\n\ts_waitcnt vmcnt(0)" : LD16_OUTS(A) : "v"(P) : "memory")

// Re-validate prefetched regs: waits all but the 4 newest (our publish-store
// acks) and REDEFINES A[] so the compiler cannot hoist tag-checks above it.
// (Data itself was drained by an earlier vmcnt(0) inside a TAGPOLL.)
#define HREVAL(A)                                                          \
  asm volatile("s_waitcnt vmcnt(4)"                                        \
    : "+v"(A[0]), "+v"(A[1]), "+v"(A[2]),  "+v"(A[3]),                     \
      "+v"(A[4]), "+v"(A[5]), "+v"(A[6]),  "+v"(A[7]),                     \
      "+v"(A[8]), "+v"(A[9]), "+v"(A[10]), "+v"(A[11]),                    \
      "+v"(A[12]),"+v"(A[13]),"+v"(A[14]), "+v"(A[15]) :: "memory")

#define TAGCHK(A, TB, BAD) do {                                            \
    _Pragma("unroll")                                                      \
    for (int q_ = 0; q_ < 16; ++q_)                                        \
      BAD |= ((u32)A[q_][0] ^ TB) | ((u32)A[q_][1] ^ TB)                   \
           | ((u32)A[q_][2] ^ TB) | ((u32)A[q_][3] ^ TB);                  \
  } while (0)

// blocking poll: wait until all 64 tags == want (LD16_W -> outputs valid)
#define TAGPOLL(A, hp, want) do {                                          \
    u32 tb = ((u32)(want)) << 16; int it_ = 0;                             \
    for (;;) {                                                             \
      LD16_W(A, hp);                                                       \
      u32 bad = 0; TAGCHK(A, tb, bad); bad &= 0xffff0000u;                 \
      if (__all(bad == 0)) break;                                          \
      if (++it_ > RETRY_LIM) break;                                        \
      __builtin_amdgcn_s_sleep(1);                                         \
    }                                                                      \
  } while (0)

__device__ __forceinline__ bf16x8 frag_from(i32x4 lo, i32x4 hi) {
  union { u32 w[4]; bf16x8 v; } u_;
  u_.w[0] = ((u32)lo[0] & 0xffffu) | ((u32)lo[1] << 16);
  u_.w[1] = ((u32)lo[2] & 0xffffu) | ((u32)lo[3] << 16);
  u_.w[2] = ((u32)hi[0] & 0xffffu) | ((u32)hi[1] << 16);
  u_.w[3] = ((u32)hi[2] & 0xffffu) | ((u32)hi[3] << 16);
  return u_.v;
}
__device__ __forceinline__ bf16x8 pack_bf8(float4 a, float4 b) {
  union { u32 w[4]; bf16x8 v; } u_;
  u_.w[0] = (u32)f2bf(a.x) | ((u32)f2bf(a.y) << 16);
  u_.w[1] = (u32)f2bf(a.z) | ((u32)f2bf(a.w) << 16);
  u_.w[2] = (u32)f2bf(b.x) | ((u32)f2bf(b.y) << 16);
  u_.w[3] = (u32)f2bf(b.z) | ((u32)f2bf(b.w) << 16);
  return u_.v;
}

// anti-dep spin (L0, every 4th step): lanes watch L1 read-progress words
__device__ __forceinline__ void spin64(const int* f, int lane, int target) {
  if (target <= 0) return;
  int it = 0;
  for (;;) {
    int v = __hip_atomic_load(&f[lane], __ATOMIC_RELAXED, __HIP_MEMORY_SCOPE_AGENT);
    if (__all(v >= target)) return;
    if (++it > SPIN_LIM) return;
    __builtin_amdgcn_s_sleep(2);
  }
}

__global__ void ws_init_kernel(int* p, int n) {
  int i = blockIdx.x * blockDim.x + threadIdx.x;
  if (i < n)    // agent-scope stores -> zeros at LLC (tag0 == h_{-1}=0)
    __hip_atomic_store(&p[i], 0, __ATOMIC_RELAXED, __HIP_MEMORY_SCOPE_AGENT);
}

// Pipelined persistent 2-layer LSTM, 128 blocks x 256 threads.
// blk<64: layer-0 worker; blk>=64: layer-1 worker (+ epilogue).
// b=blk&63: bi=b>>4 (batch group, 64 rows), j=b&15 (16-col slice).
// Wave wv = M-tile (16 rows). MFMA 16x16x32_bf16: A from tagged LLC ring
// (registers, no LDS staging), B from row-major padded LDS, C/D col=lane&15,
// row=quad*4+reg -> acc[nt]=gate nt, lane-local pointwise, c-state in VGPRs.
// L1 pipeline: h1_{t+1} prefetch issued BEFORE the blocking h2 poll, whose
// internal vmcnt(0) drains it -> at next top the h1 check is pure VALU.
__global__ void __launch_bounds__(256)
lstm_persistent(const float* __restrict__ x,
                const float* __restrict__ Wih0, const float* __restrict__ Whh0,
                const float* __restrict__ bih0, const float* __restrict__ bhh0,
                const float* __restrict__ Wih1, const float* __restrict__ Whh1,
                const float* __restrict__ bih1, const float* __restrict__ bhh1,
                const float* __restrict__ W1, const float* __restrict__ b1,
                const float* __restrict__ W2, const float* __restrict__ b2,
                float* __restrict__ out, char* __restrict__ ws)
{
  extern __shared__ u16 smem[];
  const int tid  = threadIdx.x;
  const int lane = tid & 63;
  const int wv   = tid >> 6;
  const int n16  = lane & 15;
  const int quad = lane >> 4;
  const int blk  = blockIdx.x;
  const int layer = blk >> 6;
  const int b    = blk & 63;
  const int bi   = b >> 4, j = b & 15;
  const int j16  = j * 16;
  const int rowg0 = bi * 64;
  const int widx = j*4 + wv;
  const int arow = wv*16 + n16;          // my A-row (group-local)

  u32* r1g = (u32*)(ws + WS_RING1) + (size_t)bi * 8 * 16384;   // depth 8
  u32* r2g = (u32*)(ws + WS_RING2) + (size_t)bi * 4 * 16384;   // depth 4
  int* prg = (int*)(ws + WS_PROG) + bi * 64;

  float bg[4];
  #pragma unroll
  for (int nt = 0; nt < 4; ++nt) {
    int wrow = nt*256 + j16 + n16;
    bg[nt] = layer ? (bih1[wrow] + bhh1[wrow]) : (bih0[wrow] + bhh0[wrow]);
  }
  float cst[4] = {0.f,0.f,0.f,0.f};
  i32x4 h[16];

  if (layer == 0) {
    // ---- stage W0 slice fp32->bf16 into LDS, row-major stride 328 ----
    for (int i = 0; i < 20; ++i) {
      int u = tid + i*256;               // 64 rows x 80 float4
      int lr = u / 80, c4 = u % 80;
      int wrow = (lr >> 4)*256 + j16 + (lr & 15);
      float4 v = (c4 < 16) ? *(const float4*)(Wih0 + (size_t)wrow*64 + c4*4)
                           : *(const float4*)(Whh0 + (size_t)wrow*256 + (c4-16)*4);
      u16* d = smem + lr*328 + c4*4;
      d[0]=f2bf(v.x); d[1]=f2bf(v.y); d[2]=f2bf(v.z); d[3]=f2bf(v.w);
    }
    __syncthreads();
    const u16* bP = smem + n16*328 + quad*8;

    for (int t = 0; t < NSTEPS; ++t) {
      // x_t prefetch (in flight during poll; drained by poll's vmcnt)
      const float* xp = x + ((size_t)(rowg0 + arow)*NSTEPS + t)*64 + quad*8;
      float4 xa = *(const float4*)(xp);
      float4 xb = *(const float4*)(xp + 4);
      float4 xc = *(const float4*)(xp + 32);
      float4 xd = *(const float4*)(xp + 36);
      if ((t & 3) == 0)
        spin64(prg, lane, t - 4);   // ring1 anti-dep (depth 8), every 4 steps
      { const char* hp = (const char*)(r1g + ((t+7)&7)*16384) + arow*1024 + quad*32;
        TAGPOLL(h, hp, t); }        // h1_{t-1}: tag t (t=0 -> zeros)
      bf16x8 a0 = pack_bf8(xa, xb), a1 = pack_bf8(xc, xd);
      f32x4 acc[4] = {{0,0,0,0},{0,0,0,0},{0,0,0,0},{0,0,0,0}};
      #pragma unroll
      for (int nt = 0; nt < 4; ++nt)
        acc[nt] = __builtin_amdgcn_mfma_f32_16x16x32_bf16(
            a0, *(const bf16x8*)(bP + nt*16*328), acc[nt], 0,0,0);
      #pragma unroll
      for (int nt = 0; nt < 4; ++nt)
        acc[nt] = __builtin_amdgcn_mfma_f32_16x16x32_bf16(
            a1, *(const bf16x8*)(bP + nt*16*328 + 32), acc[nt], 0,0,0);
      #pragma unroll
      for (int kc = 0; kc < 8; ++kc) {
        bf16x8 a = frag_from(h[2*kc], h[2*kc+1]);
        #pragma unroll
        for (int nt = 0; nt < 4; ++nt)
          acc[nt] = __builtin_amdgcn_mfma_f32_16x16x32_bf16(
              a, *(const bf16x8*)(bP + nt*16*328 + 64 + kc*32), acc[nt], 0,0,0);
      }
      u32 tag = ((u32)(t+1)) << 16;
      u32* dst = r1g + (t&7)*16384;
      #pragma unroll
      for (int r = 0; r < 4; ++r) {
        float gi = acc[0][r] + bg[0];
        float gf = acc[1][r] + bg[1];
        float gg = acc[2][r] + bg[2];
        float go = acc[3][r] + bg[3];
        float c  = sigf(gf)*cst[r] + sigf(gi)*tanhf_(gg);
        cst[r] = c;
        int rl = wv*16 + quad*4 + r;
        st_u32_sc1(dst + rl*256 + j16 + n16, tag | (u32)f2bf(sigf(go)*tanhf_(c)));
      }
      // no drain, no flag: consumers poll the tagged data itself
    }
    return;
  }

  // ======================= LAYER-1 WORKER =======================
  for (int i = 0; i < 32; ++i) {
    int u = tid + i*256;               // 64 rows x 128 float4 ([Wih1|Whh1])
    int lr = u >> 7, c4 = u & 127;
    int wrow = (lr >> 4)*256 + j16 + (lr & 15);
    float4 v = (c4 < 64) ? *(const float4*)(Wih1 + (size_t)wrow*256 + c4*4)
                         : *(const float4*)(Whh1 + (size_t)wrow*256 + (c4-64)*4);
    u16* d = smem + lr*520 + c4*4;
    d[0]=f2bf(v.x); d[1]=f2bf(v.y); d[2]=f2bf(v.z); d[3]=f2bf(v.w);
  }
  __syncthreads();
  const u16* bP = smem + n16*520 + quad*8;
  i32x4 g[16];

  // prologue: prefetch h1_0 (slot 0) and drain so h[] regs are defined
  { const char* p1 = (const char*)(r1g) + arow*1024 + quad*32;
    LD16_N(h, p1);
    asm volatile("s_waitcnt vmcnt(0)" ::: "memory"); }

  for (int t = 0; t < NSTEPS; ++t) {
    // h1_t check: data already in registers (prefetched + drained by the
    // previous step's h2 TAGPOLL). HREVAL redefines regs after vmcnt(4)
    // (skips our 4 in-flight publish-store acks).
    {
      HREVAL(h);
      u32 tb = ((u32)(t+1)) << 16, bad = 0;
      TAGCHK(h, tb, bad); bad &= 0xffff0000u;
      if (!__all(bad == 0)) {       // L0 behind (rare): blocking re-poll
        const char* p1 = (const char*)(r1g + (t&7)*16384) + arow*1024 + quad*32;
        TAGPOLL(h, p1, t+1);
      }
    }
    if (lane == 0)                  // read-progress for L0's anti-dep
      __hip_atomic_store(&prg[widx], t+1, __ATOMIC_RELAXED, __HIP_MEMORY_SCOPE_AGENT);
    f32x4 acc[4] = {{0,0,0,0},{0,0,0,0},{0,0,0,0},{0,0,0,0}};
    #pragma unroll
    for (int kc = 0; kc < 8; ++kc) {            // h1 half (consumes h[])
      bf16x8 a = frag_from(h[2*kc], h[2*kc+1]);
      #pragma unroll
      for (int nt = 0; nt < 4; ++nt)
        acc[nt] = __builtin_amdgcn_mfma_f32_16x16x32_bf16(
            a, *(const bf16x8*)(bP + nt*16*520 + kc*32), acc[nt], 0,0,0);
    }
    // prefetch h1_{t+1} BEFORE the blocking h2 poll; the poll's vmcnt(0)
    // drains it -> next top's check is free.
    { const char* p1n = (const char*)(r1g + ((t+1)&7)*16384) + arow*1024 + quad*32;
      LD16_N(h, p1n); }
    { const char* p2 = (const char*)(r2g + ((t+3)&3)*16384) + arow*1024 + quad*32;
      TAGPOLL(g, p2, t); }          // h2_{t-1}: tag t (the serial hop)
    #pragma unroll
    for (int kc = 0; kc < 8; ++kc) {            // h2 half
      bf16x8 a = frag_from(g[2*kc], g[2*kc+1]);
      #pragma unroll
      for (int nt = 0; nt < 4; ++nt)
        acc[nt] = __builtin_amdgcn_mfma_f32_16x16x32_bf16(
            a, *(const bf16x8*)(bP + nt*16*520 + 256 + kc*32), acc[nt], 0,0,0);
    }
    u32 tag = ((u32)(t+1)) << 16;
    u32* dst = r2g + (t&3)*16384;
    #pragma unroll
    for (int r = 0; r < 4; ++r) {
      float gi = acc[0][r] + bg[0];
      float gf = acc[1][r] + bg[1];
      float gg = acc[2][r] + bg[2];
      float go = acc[3][r] + bg[3];
      float c  = sigf(gf)*cst[r] + sigf(gi)*tanhf_(gg);
      cst[r] = c;
      int rl = wv*16 + quad*4 + r;
      st_u32_sc1(dst + rl*256 + j16 + n16, tag | (u32)f2bf(sigf(go)*tanhf_(c)));
    }
  }

  // ============ epilogue: y = (h2_T @ W1^T + b1) @ W2^T + b2 ============
  // L1 block b handles batch rows b*4..b*4+3; h2_511 = tag 512 in slot 3.
  {
    float* lastsh = (float*)smem;                 // 4x256
    float* y1sh   = lastsh + 1024;                // 4x1280
    float* psum   = y1sh + 5120;                  // 64
    __syncthreads();
    {
      int row = tid >> 6, c = tid & 63;
      int lr = (b & 15)*4 + row;                  // group-local row
      #pragma unroll
      for (int rep = 0; rep < 2; ++rep) {
        int cc = c + rep*64;                      // u64 index: cols cc*2, cc*2+1
        const u64* p = (const u64*)((const char*)(r2g + 3*16384) + lr*1024 + cc*8);
        u64 v = 0; int it = 0;
        for (;;) {
          v = ld_u64_sc1(p);
          if (((v >> 16) & 0xffffull) == 512 && (v >> 48) == 512) break;
          if (++it > RETRY_LIM) break;
          __builtin_amdgcn_s_sleep(1);
        }
        lastsh[row*256 + cc*2 + 0] = bf2f((u16)(v & 0xffffu));
        lastsh[row*256 + cc*2 + 1] = bf2f((u16)((v >> 32) & 0xffffu));
      }
    }
    __syncthreads();
    for (int i = 0; i < 5; ++i) {
      int m = tid + i*256;
      const float* wr = W1 + (size_t)m*256;
      float a0=0.f,a1=0.f,a2=0.f,a3=0.f;
      for (int k = 0; k < 256; ++k) {
        float w = wr[k];
        a0 += w*lastsh[k];     a1 += w*lastsh[256+k];
        a2 += w*lastsh[512+k]; a3 += w*lastsh[768+k];
      }
      float bb = b1[m];
      y1sh[m] = a0+bb; y1sh[1280+m] = a1+bb; y1sh[2560+m] = a2+bb; y1sh[3840+m] = a3+bb;
    }
    __syncthreads();
    if (tid < 64) {
      int row = tid >> 4, o = (tid >> 2) & 3, q = tid & 3;
      const float* w2r = W2 + (size_t)o*1280 + q*320;
      const float* yr  = y1sh + row*1280 + q*320;
      float s = 0.f;
      for (int m = 0; m < 320; ++m) s += w2r[m]*yr[m];
      psum[tid] = s;
    }
    __syncthreads();
    if (tid < 16) {
      int row = tid >> 2, o = tid & 3;
      out[(b*4 + row)*4 + o] = b2[o] + psum[tid*4+0] + psum[tid*4+1]
                                     + psum[tid*4+2] + psum[tid*4+3];
    }
  }
}

extern "C" void kernel_launch(void* const* d_in, const int* in_sizes, int n_in,
                              void* d_out, int out_size, void* d_ws, size_t ws_size,
                              hipStream_t stream) {
  (void)in_sizes; (void)n_in; (void)out_size; (void)ws_size;
  const float* x    = (const float*)d_in[0];
  const float* Wih0 = (const float*)d_in[1];
  const float* Whh0 = (const float*)d_in[2];
  const float* bih0 = (const float*)d_in[3];
  const float* bhh0 = (const float*)d_in[4];
  const float* Wih1 = (const float*)d_in[5];
  const float* Whh1 = (const float*)d_in[6];
  const float* bih1 = (const float*)d_in[7];
  const float* bhh1 = (const float*)d_in[8];
  const float* W1   = (const float*)d_in[9];
  const float* b1   = (const float*)d_in[10];
  const float* W2   = (const float*)d_in[11];
  const float* b2   = (const float*)d_in[12];
  float* out = (float*)d_out;
  char* ws   = (char*)d_ws;

  // zero rings (tag0 == h_{-1}=0) + prog flags; ws re-poisoned every call
  hipLaunchKernelGGL(ws_init_kernel, dim3((WS_TOTAL/4 + 255)/256), dim3(256),
                     0, stream, (int*)ws, (int)(WS_TOTAL/4));

  hipFuncSetAttribute((const void*)lstm_persistent,
                      hipFuncAttributeMaxDynamicSharedMemorySize, SMEM_BYTES);

  void* args[] = { (void*)&x, (void*)&Wih0, (void*)&Whh0, (void*)&bih0, (void*)&bhh0,
                   (void*)&Wih1, (void*)&Whh1, (void*)&bih1, (void*)&bhh1,
                   (void*)&W1, (void*)&b1, (void*)&W2, (void*)&b2,
                   (void*)&out, (void*)&ws };
  // cooperative launch: all 128 blocks co-resident (<= 256 CUs)
  hipLaunchCooperativeKernel((const void*)lstm_persistent, dim3(128), dim3(256),
                             args, SMEM_BYTES, stream);
}

// Round 9
// 2691.708 us; speedup vs baseline: 1.6353x; 1.0516x over previous
//
#include <hip/hip_runtime.h>
#include <stdint.h>

typedef unsigned short u16;
typedef unsigned int   u32;
typedef unsigned long long u64;
typedef __bf16 bf16_t;
typedef bf16_t bf16x8 __attribute__((ext_vector_type(8)));
typedef float  f32x4  __attribute__((ext_vector_type(4)));
typedef int    i32x4  __attribute__((ext_vector_type(4)));

#define NSTEPS 512
#define SPIN_LIM  (1<<17)
#define RETRY_LIM (1<<13)

// ---- workspace (bytes). Rings store u32 words: (step_tag<<16)|h_bf16 ->
// data is self-validating. R9 change: ring PUBLISH is global_atomic_swap
// (agent scope) -> executes at the LLC, line stays LLC-dirty-resident
// (no HBM write-through on the visibility path). Poll loads stay sc1.
#define WS_RING1 0u          /* [4 grp][4 slot][64 row][256 col] u32 h1 */
#define WS_RING2 1048576u    /* [4 grp][4 slot][64 row][256 col] u32 h2 */
#define WS_PROG  2097152u    /* [4 grp][64] int: L1 per-wave read progress */
#define WS_TOTAL 2098176u

#define SMEM_BYTES (64*520*2)   /* 66560: L1 weight slice (L0 uses 64*328*2) */

__device__ __forceinline__ u16 f2bf(float f) {
  u32 u = __float_as_uint(f);
  return (u16)((u + 0x7fffu + ((u >> 16) & 1u)) >> 16);   // RNE
}
__device__ __forceinline__ float bf2f(u16 b) { return __uint_as_float(((u32)b) << 16); }
__device__ __forceinline__ float sigf(float x) { return 1.f / (1.f + __expf(-x)); }
__device__ __forceinline__ float tanhf_(float x) {
  float e = __expf(-2.f * fabsf(x));
  float t = (1.f - e) / (1.f + e);
  return x >= 0.f ? t : -t;
}

// publish: atomic swap at agent scope -> RMW executed at the LLC,
// data visible at fabric latency, line resident for consumer polls.
__device__ __forceinline__ void pub_u32(u32* p, u32 v) {
  (void)__hip_atomic_exchange(p, v, __ATOMIC_RELAXED, __HIP_MEMORY_SCOPE_AGENT);
}
__device__ __forceinline__ u64 ld_u64_sc1(const u64* p) {
  u64 v; asm volatile("global_load_dwordx2 %0, %1, off sc1\n\ts_waitcnt vmcnt(0)"
                      : "=v"(v) : "v"(p) : "memory"); return v;
}

// 16 x 16B loads of a lane's 64 tagged words (8 chunks of 32 cols; lane
// covers cols quad*8..+7 of each chunk; row stride 1024B) + vmcnt(0).
#define LD16_W(A, P)                                                       \
  asm volatile(                                                            \
    "global_load_dwordx4 %0,  %16, off sc1\n\t"                            \
    "global_load_dwordx4 %1,  %16, off offset:16 sc1\n\t"                  \
    "global_load_dwordx4 %2,  %16, off offset:128 sc1\n\t"                 \
    "global_load_dwordx4 %3,  %16, off offset:144 sc1\n\t"                 \
    "global_load_dwordx4 %4,  %16, off offset:256 sc1\n\t"                 \
    "global_load_dwordx4 %5,  %16, off offset:272 sc1\n\t"                 \
    "global_load_dwordx4 %6,  %16, off offset:384 sc1\n\t"                 \
    "global_load_dwordx4 %7,  %16, off offset:400 sc1\n\t"                 \
    "global_load_dwordx4 %8,  %16, off offset:512 sc1\n\t"                 \
    "global_load_dwordx4 %9,  %16, off offset:528 sc1\n\t"                 \
    "global_load_dwordx4 %10, %16, off offset:640 sc1\n\t"                 \
    "global_load_dwordx4 %11, %16, off offset:656 sc1\n\t"                 \
    "global_load_dwordx4 %12, %16, off offset:768 sc1\n\t"                 \
    "global_load_dwordx4 %13, %16, off offset:784 sc1\n\t"                 \
    "global_load_dwordx4 %14, %16, off offset:896 sc1\n\t"                 \
    "global_load_dwordx4 %15, %16, off offset:912 sc1\n\t"                 \
    "s_waitcnt vmcnt(0)"                                                   \
    : "=&v"(A[0]), "=&v"(A[1]), "=&v"(A[2]),  "=&v"(A[3]),                 \
      "=&v"(A[4]), "=&v"(A[5]), "=&v"(A[6]),  "=&v"(A[7]),                 \
      "=&v"(A[8]), "=&v"(A[9]), "=&v"(A[10]), "=&v"(A[11]),                \
      "=&v"(A[12]),"=&v"(A[13]),"=&v"(A[14]), "=&v"(A[15])                 \
    : "v"(P) : "memory")

#define TAGCHK(A, TB, BAD) do {                                            \
    _Pragma("unroll")                                                      \
    for (int q_ = 0; q_ < 16; ++q_)                                        \
      BAD |= ((u32)A[q_][0] ^ TB) | ((u32)A[q_][1] ^ TB)                   \
           | ((u32)A[q_][2] ^ TB) | ((u32)A[q_][3] ^ TB);                  \
  } while (0)

// poll the data itself until every word's tag == want (self-validating sync)
#define TAGPOLL(A, hp, want) do {                                          \
    u32 tb = ((u32)(want)) << 16; int it_ = 0;                             \
    for (;;) {                                                             \
      LD16_W(A, hp);                                                       \
      u32 bad = 0; TAGCHK(A, tb, bad); bad &= 0xffff0000u;                 \
      if (__all(bad == 0)) break;                                          \
      if (++it_ > RETRY_LIM) break;                                        \
      __builtin_amdgcn_s_sleep(1);                                         \
    }                                                                      \
  } while (0)

__device__ __forceinline__ bf16x8 frag_from(i32x4 lo, i32x4 hi) {
  union { u32 w[4]; bf16x8 v; } u_;
  u_.w[0] = ((u32)lo[0] & 0xffffu) | ((u32)lo[1] << 16);
  u_.w[1] = ((u32)lo[2] & 0xffffu) | ((u32)lo[3] << 16);
  u_.w[2] = ((u32)hi[0] & 0xffffu) | ((u32)hi[1] << 16);
  u_.w[3] = ((u32)hi[2] & 0xffffu) | ((u32)hi[3] << 16);
  return u_.v;
}
__device__ __forceinline__ bf16x8 pack_bf8(float4 a, float4 b) {
  union { u32 w[4]; bf16x8 v; } u_;
  u_.w[0] = (u32)f2bf(a.x) | ((u32)f2bf(a.y) << 16);
  u_.w[1] = (u32)f2bf(a.z) | ((u32)f2bf(a.w) << 16);
  u_.w[2] = (u32)f2bf(b.x) | ((u32)f2bf(b.y) << 16);
  u_.w[3] = (u32)f2bf(b.z) | ((u32)f2bf(b.w) << 16);
  return u_.v;
}

// anti-dep spin (L0, every 2nd step): lanes watch L1 read-progress words
__device__ __forceinline__ void spin64(const int* f, int lane, int target) {
  if (target <= 0) return;
  int it = 0;
  for (;;) {
    int v = __hip_atomic_load(&f[lane], __ATOMIC_RELAXED, __HIP_MEMORY_SCOPE_AGENT);
    if (__all(v >= target)) return;
    if (++it > SPIN_LIM) return;
    __builtin_amdgcn_s_sleep(2);
  }
}

__global__ void ws_init_kernel(int* p, int n) {
  int i = blockIdx.x * blockDim.x + threadIdx.x;
  if (i < n)    // agent-scope stores -> zeros at LLC (tag0 == h_{-1}=0)
    __hip_atomic_store(&p[i], 0, __ATOMIC_RELAXED, __HIP_MEMORY_SCOPE_AGENT);
}

// Pipelined persistent 2-layer LSTM, 128 blocks x 256 threads (R6 structure).
// blk<64: layer-0 worker; blk>=64: layer-1 worker (+ epilogue).
// b=blk&63: bi=b>>4 (batch group, 64 rows), j=b&15 (16-col slice).
// Wave wv = M-tile (16 rows). MFMA 16x16x32_bf16: A from tagged LLC ring
// (registers, no LDS staging), B from row-major padded LDS, C/D col=lane&15,
// row=quad*4+reg -> acc[nt]=gate nt, lane-local pointwise, c-state in VGPRs.
// Sync: data-embedded step tags; publish via atomic-swap (LLC-resident).
__global__ void __launch_bounds__(256)
lstm_persistent(const float* __restrict__ x,
                const float* __restrict__ Wih0, const float* __restrict__ Whh0,
                const float* __restrict__ bih0, const float* __restrict__ bhh0,
                const float* __restrict__ Wih1, const float* __restrict__ Whh1,
                const float* __restrict__ bih1, const float* __restrict__ bhh1,
                const float* __restrict__ W1, const float* __restrict__ b1,
                const float* __restrict__ W2, const float* __restrict__ b2,
                float* __restrict__ out, char* __restrict__ ws)
{
  extern __shared__ u16 smem[];
  const int tid  = threadIdx.x;
  const int lane = tid & 63;
  const int wv   = tid >> 6;
  const int n16  = lane & 15;
  const int quad = lane >> 4;
  const int blk  = blockIdx.x;
  const int layer = blk >> 6;
  const int b    = blk & 63;
  const int bi   = b >> 4, j = b & 15;
  const int j16  = j * 16;
  const int rowg0 = bi * 64;
  const int widx = j*4 + wv;
  const int arow = wv*16 + n16;          // my A-row (group-local)

  u32* r1g = (u32*)(ws + WS_RING1) + (size_t)bi * 4 * 16384;
  u32* r2g = (u32*)(ws + WS_RING2) + (size_t)bi * 4 * 16384;
  int* prg = (int*)(ws + WS_PROG) + bi * 64;

  float bg[4];
  #pragma unroll
  for (int nt = 0; nt < 4; ++nt) {
    int wrow = nt*256 + j16 + n16;
    bg[nt] = layer ? (bih1[wrow] + bhh1[wrow]) : (bih0[wrow] + bhh0[wrow]);
  }
  float cst[4] = {0.f,0.f,0.f,0.f};
  i32x4 h[16];

  if (layer == 0) {
    // ---- stage W0 slice fp32->bf16 into LDS, row-major stride 328 ----
    for (int i = 0; i < 20; ++i) {
      int u = tid + i*256;               // 64 rows x 80 float4
      int lr = u / 80, c4 = u % 80;
      int wrow = (lr >> 4)*256 + j16 + (lr & 15);
      float4 v = (c4 < 16) ? *(const float4*)(Wih0 + (size_t)wrow*64 + c4*4)
                           : *(const float4*)(Whh0 + (size_t)wrow*256 + (c4-16)*4);
      u16* d = smem + lr*328 + c4*4;
      d[0]=f2bf(v.x); d[1]=f2bf(v.y); d[2]=f2bf(v.z); d[3]=f2bf(v.w);
    }
    __syncthreads();
    const u16* bP = smem + n16*328 + quad*8;

    for (int t = 0; t < NSTEPS; ++t) {
      // x_t prefetch (in flight during poll)
      const float* xp = x + ((size_t)(rowg0 + arow)*NSTEPS + t)*64 + quad*8;
      float4 xa = *(const float4*)(xp);
      float4 xb = *(const float4*)(xp + 4);
      float4 xc = *(const float4*)(xp + 32);
      float4 xd = *(const float4*)(xp + 36);
      if ((t & 1) == 0)
        spin64(prg, lane, t - 2);   // ring1 anti-dep, amortized over 2 steps
      { const char* hp = (const char*)(r1g + ((t+3)&3)*16384) + arow*1024 + quad*32;
        TAGPOLL(h, hp, t); }        // h1_{t-1}: tag t (t=0 -> zeros)
      bf16x8 a0 = pack_bf8(xa, xb), a1 = pack_bf8(xc, xd);
      f32x4 acc[4] = {{0,0,0,0},{0,0,0,0},{0,0,0,0},{0,0,0,0}};
      #pragma unroll
      for (int nt = 0; nt < 4; ++nt)
        acc[nt] = __builtin_amdgcn_mfma_f32_16x16x32_bf16(
            a0, *(const bf16x8*)(bP + nt*16*328), acc[nt], 0,0,0);
      #pragma unroll
      for (int nt = 0; nt < 4; ++nt)
        acc[nt] = __builtin_amdgcn_mfma_f32_16x16x32_bf16(
            a1, *(const bf16x8*)(bP + nt*16*328 + 32), acc[nt], 0,0,0);
      #pragma unroll
      for (int kc = 0; kc < 8; ++kc) {
        bf16x8 a = frag_from(h[2*kc], h[2*kc+1]);
        #pragma unroll
        for (int nt = 0; nt < 4; ++nt)
          acc[nt] = __builtin_amdgcn_mfma_f32_16x16x32_bf16(
              a, *(const bf16x8*)(bP + nt*16*328 + 64 + kc*32), acc[nt], 0,0,0);
      }
      u32 tag = ((u32)(t+1)) << 16;
      u32* dst = r1g + (t&3)*16384;
      #pragma unroll
      for (int r = 0; r < 4; ++r) {
        float gi = acc[0][r] + bg[0];
        float gf = acc[1][r] + bg[1];
        float gg = acc[2][r] + bg[2];
        float go = acc[3][r] + bg[3];
        float c  = sigf(gf)*cst[r] + sigf(gi)*tanhf_(gg);
        cst[r] = c;
        int rl = wv*16 + quad*4 + r;
        pub_u32(dst + rl*256 + j16 + n16, tag | (u32)f2bf(sigf(go)*tanhf_(c)));
      }
      // no drain, no flag: consumers poll the tagged data itself
    }
    return;
  }

  // ======================= LAYER-1 WORKER =======================
  for (int i = 0; i < 32; ++i) {
    int u = tid + i*256;               // 64 rows x 128 float4 ([Wih1|Whh1])
    int lr = u >> 7, c4 = u & 127;
    int wrow = (lr >> 4)*256 + j16 + (lr & 15);
    float4 v = (c4 < 64) ? *(const float4*)(Wih1 + (size_t)wrow*256 + c4*4)
                         : *(const float4*)(Whh1 + (size_t)wrow*256 + (c4-64)*4);
    u16* d = smem + lr*520 + c4*4;
    d[0]=f2bf(v.x); d[1]=f2bf(v.y); d[2]=f2bf(v.z); d[3]=f2bf(v.w);
  }
  __syncthreads();
  const u16* bP = smem + n16*520 + quad*8;
  i32x4 g[16];

  for (int t = 0; t < NSTEPS; ++t) {
    { const char* hp = (const char*)(r1g + (t&3)*16384) + arow*1024 + quad*32;
      TAGPOLL(h, hp, t+1); }        // h1_t (L0 leads; usually 1 poll)
    if (lane == 0)                  // read-progress for L0's anti-dep
      __hip_atomic_store(&prg[widx], t+1, __ATOMIC_RELAXED, __HIP_MEMORY_SCOPE_AGENT);
    f32x4 acc[4] = {{0,0,0,0},{0,0,0,0},{0,0,0,0},{0,0,0,0}};
    #pragma unroll
    for (int kc = 0; kc < 8; ++kc) {            // h1 half off the h2 cycle
      bf16x8 a = frag_from(h[2*kc], h[2*kc+1]);
      #pragma unroll
      for (int nt = 0; nt < 4; ++nt)
        acc[nt] = __builtin_amdgcn_mfma_f32_16x16x32_bf16(
            a, *(const bf16x8*)(bP + nt*16*520 + kc*32), acc[nt], 0,0,0);
    }
    { const char* hp = (const char*)(r2g + ((t+3)&3)*16384) + arow*1024 + quad*32;
      TAGPOLL(g, hp, t); }          // h2_{t-1}: tag t
    #pragma unroll
    for (int kc = 0; kc < 8; ++kc) {
      bf16x8 a = frag_from(g[2*kc], g[2*kc+1]);
      #pragma unroll
      for (int nt = 0; nt < 4; ++nt)
        acc[nt] = __builtin_amdgcn_mfma_f32_16x16x32_bf16(
            a, *(const bf16x8*)(bP + nt*16*520 + 256 + kc*32), acc[nt], 0,0,0);
    }
    u32 tag = ((u32)(t+1)) << 16;
    u32* dst = r2g + (t&3)*16384;
    #pragma unroll
    for (int r = 0; r < 4; ++r) {
      float gi = acc[0][r] + bg[0];
      float gf = acc[1][r] + bg[1];
      float gg = acc[2][r] + bg[2];
      float go = acc[3][r] + bg[3];
      float c  = sigf(gf)*cst[r] + sigf(gi)*tanhf_(gg);
      cst[r] = c;
      int rl = wv*16 + quad*4 + r;
      pub_u32(dst + rl*256 + j16 + n16, tag | (u32)f2bf(sigf(go)*tanhf_(c)));
    }
  }

  // ============ epilogue: y = (h2_T @ W1^T + b1) @ W2^T + b2 ============
  // L1 block b handles batch rows b*4..b*4+3; h2_511 = tag 512 in slot 3.
  {
    float* lastsh = (float*)smem;                 // 4x256
    float* y1sh   = lastsh + 1024;                // 4x1280
    float* psum   = y1sh + 5120;                  // 64
    __syncthreads();
    {
      int row = tid >> 6, c = tid & 63;
      int lr = (b & 15)*4 + row;                  // group-local row
      #pragma unroll
      for (int rep = 0; rep < 2; ++rep) {
        int cc = c + rep*64;                      // u64 index: cols cc*2, cc*2+1
        const u64* p = (const u64*)((const char*)(r2g + 3*16384) + lr*1024 + cc*8);
        u64 v = 0; int it = 0;
        for (;;) {
          v = ld_u64_sc1(p);
          if (((v >> 16) & 0xffffull) == 512 && (v >> 48) == 512) break;
          if (++it > RETRY_LIM) break;
          __builtin_amdgcn_s_sleep(1);
        }
        lastsh[row*256 + cc*2 + 0] = bf2f((u16)(v & 0xffffu));
        lastsh[row*256 + cc*2 + 1] = bf2f((u16)((v >> 32) & 0xffffu));
      }
    }
    __syncthreads();
    for (int i = 0; i < 5; ++i) {
      int m = tid + i*256;
      const float* wr = W1 + (size_t)m*256;
      float a0=0.f,a1=0.f,a2=0.f,a3=0.f;
      for (int k = 0; k < 256; ++k) {
        float w = wr[k];
        a0 += w*lastsh[k];     a1 += w*lastsh[256+k];
        a2 += w*lastsh[512+k]; a3 += w*lastsh[768+k];
      }
      float bb = b1[m];
      y1sh[m] = a0+bb; y1sh[1280+m] = a1+bb; y1sh[2560+m] = a2+bb; y1sh[3840+m] = a3+bb;
    }
    __syncthreads();
    if (tid < 64) {
      int row = tid >> 4, o = (tid >> 2) & 3, q = tid & 3;
      const float* w2r = W2 + (size_t)o*1280 + q*320;
      const float* yr  = y1sh + row*1280 + q*320;
      float s = 0.f;
      for (int m = 0; m < 320; ++m) s += w2r[m]*yr[m];
      psum[tid] = s;
    }
    __syncthreads();
    if (tid < 16) {
      int row = tid >> 2, o = tid & 3;
      out[(b*4 + row)*4 + o] = b2[o] + psum[tid*4+0] + psum[tid*4+1]
                                     + psum[tid*4+2] + psum[tid*4+3];
    }
  }
}

extern "C" void kernel_launch(void* const* d_in, const int* in_sizes, int n_in,
                              void* d_out, int out_size, void* d_ws, size_t ws_size,
                              hipStream_t stream) {
  (void)in_sizes; (void)n_in; (void)out_size; (void)ws_size;
  const float* x    = (const float*)d_in[0];
  const float* Wih0 = (const float*)d_in[1];
  const float* Whh0 = (const float*)d_in[2];
  const float* bih0 = (const float*)d_in[3];
  const float* bhh0 = (const float*)d_in[4];
  const float* Wih1 = (const float*)d_in[5];
  const float* Whh1 = (const float*)d_in[6];
  const float* bih1 = (const float*)d_in[7];
  const float* bhh1 = (const float*)d_in[8];
  const float* W1   = (const float*)d_in[9];
  const float* b1   = (const float*)d_in[10];
  const float* W2   = (const float*)d_in[11];
  const float* b2   = (const float*)d_in[12];
  float* out = (float*)d_out;
  char* ws   = (char*)d_ws;

  // zero rings (tag0 == h_{-1}=0) + prog flags; ws re-poisoned every call
  hipLaunchKernelGGL(ws_init_kernel, dim3((WS_TOTAL/4 + 255)/256), dim3(256),
                     0, stream, (int*)ws, (int)(WS_TOTAL/4));

  hipFuncSetAttribute((const void*)lstm_persistent,
                      hipFuncAttributeMaxDynamicSharedMemorySize, SMEM_BYTES);

  void* args[] = { (void*)&x, (void*)&Wih0, (void*)&Whh0, (void*)&bih0, (void*)&bhh0,
                   (void*)&Wih1, (void*)&Whh1, (void*)&bih1, (void*)&bhh1,
                   (void*)&W1, (void*)&b1, (void*)&W2, (void*)&b2,
                   (void*)&out, (void*)&ws };
  // cooperative launch: all 128 blocks co-resident (<= 256 CUs)
  hipLaunchCooperativeKernel((const void*)lstm_persistent, dim3(128), dim3(256),
                             args, SMEM_BYTES, stream);
}